// Round 17
// baseline (452.275 us; speedup 1.0000x reference)
//
#include <hip/hip_runtime.h>
#include <hip/hip_bf16.h>
#include <math.h>

#define NND 20000      // nodes
#define NE  1000000    // edges
#define RREL 32        // relations
#define HD 128         // hidden / in dim
#define NB 8           // bases
#define NT 20000       // target edges
#define KCAT 1152      // B*IN + IN  (mb || x)
#define NBLK 128       // histogram-sort blocks
#define CHUNK ((NE + NBLK - 1) / NBLK)   // 7813 edges per block (< 65536 -> u16 counts safe)

#define ETYPE_BLKS ((NE + 255)/256)          // 3907
#define CASTX_BLKS ((NND*HD/8 + 255)/256)    // 1250
#define PREPW_BLKS ((HD*(KCAT/8) + 255)/256) // 72
#define PREP_BLKS  (RREL*8)                  // 256

typedef short bf16x8 __attribute__((ext_vector_type(8)));
typedef float f32x4 __attribute__((ext_vector_type(4)));
typedef float f32x2 __attribute__((ext_vector_type(2)));

static __device__ __forceinline__ unsigned short f2bf(float f){
  union { float f; unsigned int u; } c; c.f = f;
  unsigned int r = c.u + 0x7FFF + ((c.u >> 16) & 1);   // RNE
  return (unsigned short)(r >> 16);
}
static __device__ __forceinline__ float bf2f(unsigned short s){
  union { unsigned int u; float f; } c; c.u = ((unsigned int)s) << 16;
  return c.f;
}

// ---------- fused setup: etype | castX | prepW1 | prepW2 | prep(Ms) ----------
__global__ __launch_bounds__(256) void k_setup(
    const float* __restrict__ ea, int* __restrict__ etype,
    const float* __restrict__ x, unsigned short* __restrict__ xb,
    const float* __restrict__ bases1, const float* __restrict__ root1, unsigned short* __restrict__ Wt1,
    const float* __restrict__ bases2, const float* __restrict__ root2, unsigned short* __restrict__ Wt2,
    const float* __restrict__ Rm, const float* __restrict__ D, unsigned short* __restrict__ Ms)
{
  int bid = blockIdx.x;
  int t = threadIdx.x;
  if (bid < ETYPE_BLKS){
    int e = bid*256 + t;
    if (e >= NE) return;
    const float4* row = (const float4*)(ea + (size_t)e*RREL);
    int bi = 0;
    #pragma unroll
    for (int q=0;q<8;q++){
      float4 v = row[q];
      if (v.x > 0.5f) bi = q*4;
      if (v.y > 0.5f) bi = q*4+1;
      if (v.z > 0.5f) bi = q*4+2;
      if (v.w > 0.5f) bi = q*4+3;
    }
    etype[e] = bi;
    return;
  }
  bid -= ETYPE_BLKS;
  if (bid < CASTX_BLKS){
    int i = bid*256 + t;
    if (i >= NND*HD/8) return;
    const float4* p = (const float4*)(x + (size_t)i*8);
    float4 a = p[0], b = p[1];
    unsigned int o0 = f2bf(a.x) | ((unsigned int)f2bf(a.y)<<16);
    unsigned int o1 = f2bf(a.z) | ((unsigned int)f2bf(a.w)<<16);
    unsigned int o2 = f2bf(b.x) | ((unsigned int)f2bf(b.y)<<16);
    unsigned int o3 = f2bf(b.z) | ((unsigned int)f2bf(b.w)<<16);
    *(uint4*)(xb + (size_t)i*8) = make_uint4(o0,o1,o2,o3);
    return;
  }
  bid -= CASTX_BLKS;
  if (bid < 2*PREPW_BLKS){
    const float* bases = (bid < PREPW_BLKS) ? bases1 : bases2;
    const float* root  = (bid < PREPW_BLKS) ? root1  : root2;
    unsigned short* Wt = (bid < PREPW_BLKS) ? Wt1    : Wt2;
    int idx = (bid % PREPW_BLKS)*256 + t;
    if (idx >= HD*(KCAT/8)) return;
    int o  = idx / (KCAT/8);
    int k0 = (idx % (KCAT/8))*8;
    unsigned short tmp[8];
    #pragma unroll
    for (int q=0;q<8;q++){
      int k = k0+q;
      float v = (k < 1024) ? bases[(size_t)k*HD + o] : root[(size_t)(k-1024)*HD + o];
      tmp[q] = f2bf(v);
    }
    *(uint4*)(Wt + (size_t)o*KCAT + k0) = *(uint4*)tmp;
    return;
  }
  bid -= 2*PREPW_BLKS;
  {
    int r = bid & 31, ib = bid >> 5;
    int i = ib*16 + (t>>4);
    int j0 = (t&15)*8;
    float di = D[r*HD + i];
    float4 dj0 = *(const float4*)(D + r*HD + j0);
    float4 dj1 = *(const float4*)(D + r*HD + j0 + 4);
    float4 r0 = *(const float4*)(Rm + (size_t)i*HD + j0);
    float4 r1 = *(const float4*)(Rm + (size_t)i*HD + j0 + 4);
    unsigned int o0 = f2bf(di*dj0.x*r0.x) | ((unsigned int)f2bf(di*dj0.y*r0.y)<<16);
    unsigned int o1 = f2bf(di*dj0.z*r0.z) | ((unsigned int)f2bf(di*dj0.w*r0.w)<<16);
    unsigned int o2 = f2bf(di*dj1.x*r1.x) | ((unsigned int)f2bf(di*dj1.y*r1.y)<<16);
    unsigned int o3 = f2bf(di*dj1.z*r1.z) | ((unsigned int)f2bf(di*dj1.w*r1.w)<<16);
    *(uint4*)(Ms + (size_t)(r*HD + i)*HD + j0) = make_uint4(o0,o1,o2,o3);
  }
}

// ---------- per-block dst histogram (LDS, u16-packed) -> ghist[n][b] ----------
__global__ __launch_bounds__(1024) void k_hist(const int* __restrict__ ei,
                                               int* __restrict__ ghist)
{
  __shared__ int h[NND/2];   // 40 KB, two u16 counts per int
  int t = threadIdx.x, b = blockIdx.x;
  for (int i=t; i<NND/2; i+=1024) h[i] = 0;
  __syncthreads();
  int e0 = b*CHUNK, e1 = min(e0+CHUNK, NE);
  for (int e=e0+t; e<e1; e+=1024){
    int dst = ei[NE + e];
    atomicAdd(&h[dst>>1], 1 << ((dst&1)*16));
  }
  __syncthreads();
  for (int i=t; i<NND/2; i+=1024){
    int v = h[i];
    ghist[(size_t)(2*i  )*NBLK + b] = v & 0xFFFF;
    ghist[(size_t)(2*i+1)*NBLK + b] = (v >> 16) & 0xFFFF;
  }
}

// ---------- node_cnt[n] = sum_b ghist[n][b]  (wave per node, 2 elems/lane) ----------
__global__ __launch_bounds__(256) void k_rowsum(const int* __restrict__ ghist,
                                                int* __restrict__ node_cnt)
{
  int t = threadIdx.x;
  int n = blockIdx.x*4 + (t>>6);
  int lane = t & 63;
  int v = ghist[(size_t)n*NBLK + lane] + ghist[(size_t)n*NBLK + 64 + lane];
  #pragma unroll
  for (int d=32; d>0; d>>=1) v += __shfl_down(v, d);
  if (lane == 0) node_cnt[n] = v;
}

// ---------- single-block exclusive scan of node_cnt -> node_off ----------
__global__ __launch_bounds__(1024) void k_scan(const int* __restrict__ node_cnt,
                                               int* __restrict__ node_off)
{
  __shared__ int part[1024];
  int t = threadIdx.x;
  const int CH = (NND + 1023)/1024;   // 20
  int base = t*CH;
  int s = 0;
  for (int i=0;i<CH;i++){ int idx = base+i; if (idx<NND) s += node_cnt[idx]; }
  part[t] = s;
  __syncthreads();
  for (int d=1; d<1024; d<<=1){
    int v = part[t];
    int u = (t>=d) ? part[t-d] : 0;
    __syncthreads();
    part[t] = v + u;
    __syncthreads();
  }
  int run = (t==0) ? 0 : part[t-1];
  for (int i=0;i<CH;i++){ int idx=base+i; if (idx<NND){ node_off[idx]=run; run += node_cnt[idx]; } }
  if (t==1023) node_off[NND] = part[1023];
}

// ---------- ghist[n][b] -> absolute scatter base (128 entries: 2 elems/lane) ----------
__global__ __launch_bounds__(256) void k_scanB(int* __restrict__ ghist,
                                               const int* __restrict__ node_off)
{
  int t = threadIdx.x;
  int n = blockIdx.x*4 + (t>>6);
  int lane = t & 63;
  int v0 = ghist[(size_t)n*NBLK + lane];
  int v1 = ghist[(size_t)n*NBLK + 64 + lane];
  int x0 = v0, x1 = v1;
  #pragma unroll
  for (int d=1; d<64; d<<=1){
    int y0 = __shfl_up(x0, d);
    int y1 = __shfl_up(x1, d);
    if (lane >= d){ x0 += y0; x1 += y1; }
  }
  int T0 = __shfl(x0, 63);     // total of first 64 entries
  x1 += T0;
  int off = node_off[n];
  ghist[(size_t)n*NBLK + lane]      = off + x0 - v0;   // exclusive prefix
  ghist[(size_t)n*NBLK + 64 + lane] = off + x1 - v1;
}

// ---------- scatter replay: rank via LDS atomics, no global atomics ----------
__global__ __launch_bounds__(1024) void k_scatter2(
    const int* __restrict__ ei, const int* __restrict__ etype,
    const int* __restrict__ ghist, int2* __restrict__ sorted)
{
  __shared__ int h[NND/2];
  int t = threadIdx.x, b = blockIdx.x;
  for (int i=t; i<NND/2; i+=1024) h[i] = 0;
  __syncthreads();
  int e0 = b*CHUNK, e1 = min(e0+CHUNK, NE);
  for (int e=e0+t; e<e1; e+=1024){
    int dst = ei[NE + e];
    int sh = (dst&1)*16;
    int old = atomicAdd(&h[dst>>1], 1 << sh);
    int rank = (old >> sh) & 0xFFFF;
    int pos = ghist[(size_t)dst*NBLK + b] + rank;
    sorted[pos] = make_int2(ei[e], etype[e]);
  }
}

// ---------- per-(node,rel) counts -> fused compic tables: compic[n][r][b]=comp[r][b]/max(cnt,1) ----------
__global__ __launch_bounds__(256) void k_cnt(const int2* __restrict__ sorted,
                                             const int* __restrict__ node_off,
                                             const float* __restrict__ comp1,
                                             const float* __restrict__ comp2,
                                             float* __restrict__ compic1,
                                             float* __restrict__ compic2)
{
  int t = threadIdx.x;
  int n = blockIdx.x*4 + (t>>6);
  int lane = t & 63;
  int r = lane & 31, half = lane >> 5;
  int p0 = node_off[n], p1 = node_off[n+1];
  int c = 0;
  for (int p=p0+half; p<p1; p+=2) c += (sorted[p].y == r);
  c += __shfl_down(c, 32);
  if (lane < 32){
    float ic = 1.0f / fmaxf((float)c, 1.0f);
    const float4* c1 = (const float4*)(comp1 + lane*NB);
    const float4* c2 = (const float4*)(comp2 + lane*NB);
    float4 a1 = c1[0], b1 = c1[1];
    float4 a2 = c2[0], b2 = c2[1];
    float4* o1 = (float4*)(compic1 + ((size_t)n*RREL + lane)*NB);
    float4* o2 = (float4*)(compic2 + ((size_t)n*RREL + lane)*NB);
    o1[0] = make_float4(a1.x*ic, a1.y*ic, a1.z*ic, a1.w*ic);
    o1[1] = make_float4(b1.x*ic, b1.y*ic, b1.z*ic, b1.w*ic);
    o2[0] = make_float4(a2.x*ic, a2.y*ic, a2.z*ic, a2.w*ic);
    o2[1] = make_float4(b2.x*ic, b2.y*ic, b2.z*ic, b2.w*ic);
  }
}

// ---------- per-node aggregation: 1 wave/block (CLOSED structure), 2-edge unroll, compic coefficients ----------
__global__ __launch_bounds__(64) void k_agg(
    const int2* __restrict__ sorted, const int* __restrict__ node_off,
    const float* __restrict__ compic,
    const unsigned short* __restrict__ xb, unsigned short* __restrict__ mbxb)
{
  int n = blockIdx.x;
  int lane = threadIdx.x;
  f32x2 acc[NB];
  #pragma unroll
  for (int b=0;b<NB;b++){ f32x2 z = {0.f,0.f}; acc[b] = z; }
  int p0 = node_off[n], p1 = node_off[n+1];
  const float* cic = compic + (size_t)n*RREL*NB;

  int p = p0;
  if ((p & 1) && p < p1){
    int2 se = sorted[p];
    unsigned int vv = *(const unsigned int*)(xb + (size_t)se.x*HD + 2*lane);
    const float4* cr = (const float4*)(cic + se.y*NB);
    float4 c0 = cr[0], c1 = cr[1];
    f32x2 xv = { bf2f((unsigned short)(vv & 0xFFFF)),
                 bf2f((unsigned short)(vv >> 16)) };
    acc[0] += c0.x*xv; acc[1] += c0.y*xv; acc[2] += c0.z*xv; acc[3] += c0.w*xv;
    acc[4] += c1.x*xv; acc[5] += c1.y*xv; acc[6] += c1.z*xv; acc[7] += c1.w*xv;
    ++p;
  }
  for (; p + 2 <= p1; p += 2){
    int4 s2 = *(const int4*)(sorted + p);   // edge A=(x,y), edge B=(z,w)
    unsigned int va = *(const unsigned int*)(xb + (size_t)s2.x*HD + 2*lane);
    unsigned int vb = *(const unsigned int*)(xb + (size_t)s2.z*HD + 2*lane);
    const float4* crA = (const float4*)(cic + s2.y*NB);
    const float4* crB = (const float4*)(cic + s2.w*NB);
    float4 cA0 = crA[0], cA1 = crA[1];
    float4 cB0 = crB[0], cB1 = crB[1];
    f32x2 xa = { bf2f((unsigned short)(va & 0xFFFF)),
                 bf2f((unsigned short)(va >> 16)) };
    f32x2 xv = { bf2f((unsigned short)(vb & 0xFFFF)),
                 bf2f((unsigned short)(vb >> 16)) };
    acc[0] += cA0.x*xa; acc[1] += cA0.y*xa; acc[2] += cA0.z*xa; acc[3] += cA0.w*xa;
    acc[4] += cA1.x*xa; acc[5] += cA1.y*xa; acc[6] += cA1.z*xa; acc[7] += cA1.w*xa;
    acc[0] += cB0.x*xv; acc[1] += cB0.y*xv; acc[2] += cB0.z*xv; acc[3] += cB0.w*xv;
    acc[4] += cB1.x*xv; acc[5] += cB1.y*xv; acc[6] += cB1.z*xv; acc[7] += cB1.w*xv;
  }
  if (p < p1){
    int2 se = sorted[p];
    unsigned int vv = *(const unsigned int*)(xb + (size_t)se.x*HD + 2*lane);
    const float4* cr = (const float4*)(cic + se.y*NB);
    float4 c0 = cr[0], c1 = cr[1];
    f32x2 xv = { bf2f((unsigned short)(vv & 0xFFFF)),
                 bf2f((unsigned short)(vv >> 16)) };
    acc[0] += c0.x*xv; acc[1] += c0.y*xv; acc[2] += c0.z*xv; acc[3] += c0.w*xv;
    acc[4] += c1.x*xv; acc[5] += c1.y*xv; acc[6] += c1.z*xv; acc[7] += c1.w*xv;
  }

  unsigned short* o = mbxb + (size_t)n*KCAT;
  #pragma unroll
  for (int b=0;b<NB;b++){
    unsigned int u = (unsigned int)f2bf(acc[b][0]) | ((unsigned int)f2bf(acc[b][1])<<16);
    *(unsigned int*)(o + b*HD + 2*lane) = u;
  }
  *(unsigned int*)(o + 1024 + 2*lane) = *(const unsigned int*)(xb + (size_t)n*HD + 2*lane);
}

// ---------- layer GEMM via MFMA: 16 rows/block, bf16 output only ----------
__global__ __launch_bounds__(256) void k_gemm2(
    const unsigned short* __restrict__ A, const unsigned short* __restrict__ Wt,
    const float* __restrict__ bias, unsigned short* __restrict__ outB)
{
  int t = threadIdx.x, bm = blockIdx.x;       // bm in [0,1250): rows bm*16..bm*16+15
  int lane = t & 63, w = t >> 6, g = lane >> 4, c = lane & 15;
  const unsigned short* arow = A + (size_t)(bm*16 + c)*KCAT;
  const unsigned short* wt0 = Wt + (size_t)((w*2+0)*16 + c)*KCAT;
  const unsigned short* wt1 = Wt + (size_t)((w*2+1)*16 + c)*KCAT;
  f32x4 acc0 = {0.f,0.f,0.f,0.f}, acc1 = {0.f,0.f,0.f,0.f};
  #pragma unroll 4
  for (int kk=0; kk<KCAT/32; ++kk){
    int koff = kk*32 + 8*g;
    bf16x8 a  = *(const bf16x8*)(arow + koff);
    bf16x8 b0 = *(const bf16x8*)(wt0 + koff);
    bf16x8 b1 = *(const bf16x8*)(wt1 + koff);
    acc0 = __builtin_amdgcn_mfma_f32_16x16x32_bf16(a, b0, acc0, 0,0,0);
    acc1 = __builtin_amdgcn_mfma_f32_16x16x32_bf16(a, b1, acc1, 0,0,0);
  }
  int orow = bm*16 + 4*g;
  #pragma unroll
  for (int nt=0; nt<2; ++nt){
    int o = (w*2+nt)*16 + c;
    float bi = bias[o];
    f32x4 acc = nt ? acc1 : acc0;
    #pragma unroll
    for (int q=0; q<4; ++q){
      int rr = orow + q;
      outB[(size_t)rr*HD + o] = f2bf(fmaxf(acc[q] + bi, 0.f));
    }
  }
}

// ---------- DEDICOM decoder via MFMA: 64 edges x 8 relations per block, u(bf16) in registers ----------
// grid (313, 4). LDS: vb 17.4 KB + red 1.2 KB. blockIdx.y*8+rr = relation.
__global__ __launch_bounds__(256) void k_dec3(
    const unsigned short* __restrict__ h2b, const int* __restrict__ tgt,
    const unsigned short* __restrict__ Ms, float* __restrict__ out)
{
  __shared__ __align__(16) unsigned short vb[64*136];  // v rows bf16, pad 136 (2-way max)
  __shared__ __align__(16) float red[4][72];           // per-wave partials, conflict-free
  int t = threadIdx.x;
  int bm = blockIdx.x;
  int lane = t & 63, w = t >> 6, g = lane >> 4, c = lane & 15;

  // stage v rows: direct bf16 copy from h2b
  {
    int e = t >> 2, seg = t & 3;
    int eg = bm*64 + e;
    bool ok = (eg < NT);
    int n1 = ok ? tgt[NT + eg] : 0;
    const uint4* pv = (const uint4*)(h2b + (size_t)n1*HD);   // 16 uint4 per row
    unsigned int* vbr = (unsigned int*)vb + e*68;
    #pragma unroll
    for (int q=0; q<4; ++q){
      uint4 v4 = ok ? pv[seg*4+q] : make_uint4(0,0,0,0);
      *(uint4*)(vbr + (seg*4+q)*4) = v4;
    }
  }
  // u rows in registers (r-invariant), loaded bf16 and converted once
  float4 ur[4][2];
  #pragma unroll
  for (int nt=0; nt<4; ++nt){
    int eg = bm*64 + nt*16 + c;
    bool ok = (eg < NT);
    int n0 = ok ? tgt[eg] : 0;
    const unsigned short* pu = h2b + (size_t)n0*HD;
    #pragma unroll
    for (int mm=0; mm<2; ++mm){
      uint2 uu = ok ? *(const uint2*)(pu + (2*w+mm)*16 + 4*g) : make_uint2(0,0);
      ur[nt][mm] = make_float4(
        bf2f((unsigned short)(uu.x & 0xFFFF)), bf2f((unsigned short)(uu.x >> 16)),
        bf2f((unsigned short)(uu.y & 0xFFFF)), bf2f((unsigned short)(uu.y >> 16)));
    }
  }
  __syncthreads();

  for (int rr=0; rr<8; ++rr){
    int r = blockIdx.y*8 + rr;
    f32x4 acc[2][4];
    #pragma unroll
    for (int mm=0;mm<2;mm++)
      #pragma unroll
      for (int nt=0;nt<4;nt++){ f32x4 z = {0.f,0.f,0.f,0.f}; acc[mm][nt] = z; }
    #pragma unroll
    for (int kk=0; kk<4; ++kk){
      int koff = kk*32 + 8*g;
      bf16x8 a0 = *(const bf16x8*)(Ms + (size_t)(r*HD + (2*w+0)*16 + c)*HD + koff);
      bf16x8 a1 = *(const bf16x8*)(Ms + (size_t)(r*HD + (2*w+1)*16 + c)*HD + koff);
      #pragma unroll
      for (int nt=0; nt<4; ++nt){
        bf16x8 b = *(const bf16x8*)&vb[(nt*16 + c)*136 + koff];
        acc[0][nt] = __builtin_amdgcn_mfma_f32_16x16x32_bf16(a0, b, acc[0][nt], 0,0,0);
        acc[1][nt] = __builtin_amdgcn_mfma_f32_16x16x32_bf16(a1, b, acc[1][nt], 0,0,0);
      }
    }
    float s[4];
    #pragma unroll
    for (int nt=0; nt<4; ++nt){
      s[nt] = ur[nt][0].x*acc[0][nt][0] + ur[nt][0].y*acc[0][nt][1]
            + ur[nt][0].z*acc[0][nt][2] + ur[nt][0].w*acc[0][nt][3]
            + ur[nt][1].x*acc[1][nt][0] + ur[nt][1].y*acc[1][nt][1]
            + ur[nt][1].z*acc[1][nt][2] + ur[nt][1].w*acc[1][nt][3];
      s[nt] += __shfl_xor(s[nt], 16);
      s[nt] += __shfl_xor(s[nt], 32);
    }
    if (lane < 16){
      #pragma unroll
      for (int nt=0; nt<4; ++nt) red[w][nt*16 + lane] = s[nt];
    }
    __syncthreads();
    if (t < 64){
      float sum = red[0][t] + red[1][t] + red[2][t] + red[3][t];
      int eg = bm*64 + t;
      if (eg < NT) out[(size_t)eg*RREL + r] = 1.f/(1.f+expf(-sum));
    }
    __syncthreads();
  }
}

extern "C" void kernel_launch(void* const* d_in, const int* in_sizes, int n_in,
                              void* d_out, int out_size, void* d_ws, size_t ws_size,
                              hipStream_t stream)
{
  const float* x      = (const float*)d_in[0];
  const int*   ei     = (const int*)d_in[1];     // int32 (harness converts integer inputs)
  const float* ea     = (const float*)d_in[2];
  const int*   tgt    = (const int*)d_in[3];     // int32
  const float* bases1 = (const float*)d_in[4];
  const float* comp1  = (const float*)d_in[5];
  const float* root1  = (const float*)d_in[6];
  const float* bias1  = (const float*)d_in[7];
  const float* bases2 = (const float*)d_in[8];
  const float* comp2  = (const float*)d_in[9];
  const float* root2  = (const float*)d_in[10];
  const float* bias2  = (const float*)d_in[11];
  const float* Rm     = (const float*)d_in[12];
  const float* D      = (const float*)d_in[13];
  float* out = (float*)d_out;

  char* base = (char*)d_ws;
  size_t o = 0;
  auto carve = [&](size_t bytes)->char*{
    char* p = base + o;
    o += (bytes + 255) & ~(size_t)255;
    return p;
  };
  int*   etype     = (int*)  carve((size_t)NE*4);
  int*   ghist     = (int*)  carve((size_t)NND*NBLK*4);
  float* compic1   = (float*)carve((size_t)NND*RREL*NB*4);
  float* compic2   = (float*)carve((size_t)NND*RREL*NB*4);
  int*   node_cnt  = (int*)  carve((size_t)NND*4);
  int*   node_off  = (int*)  carve((size_t)(NND+1)*4);
  int2*  sorted    = (int2*) carve((size_t)NE*8);
  unsigned short* mbxb = (unsigned short*)carve((size_t)NND*KCAT*2);
  unsigned short* xb  = (unsigned short*)carve((size_t)NND*HD*2);
  unsigned short* h1b = (unsigned short*)carve((size_t)NND*HD*2);
  unsigned short* h2b = (unsigned short*)carve((size_t)NND*HD*2);
  unsigned short* Ms  = (unsigned short*)carve((size_t)RREL*HD*HD*2);
  unsigned short* Wt1 = (unsigned short*)carve((size_t)HD*KCAT*2);
  unsigned short* Wt2 = (unsigned short*)carve((size_t)HD*KCAT*2);

  if (ws_size < o) return;   // workspace too small: fail loudly (wrong output, no corruption)

  int setup_blks = ETYPE_BLKS + CASTX_BLKS + 2*PREPW_BLKS + PREP_BLKS;
  k_setup <<<setup_blks, 256, 0, stream>>>(ea, etype, x, xb,
                                           bases1, root1, Wt1,
                                           bases2, root2, Wt2,
                                           Rm, D, Ms);
  k_hist    <<<NBLK, 1024, 0, stream>>>(ei, ghist);
  k_rowsum  <<<NND/4, 256, 0, stream>>>(ghist, node_cnt);
  k_scan    <<<1, 1024, 0, stream>>>(node_cnt, node_off);
  k_scanB   <<<NND/4, 256, 0, stream>>>(ghist, node_off);
  k_scatter2<<<NBLK, 1024, 0, stream>>>(ei, etype, ghist, sorted);
  k_cnt     <<<NND/4, 256, 0, stream>>>(sorted, node_off, comp1, comp2, compic1, compic2);

  k_agg  <<<NND, 64, 0, stream>>>(sorted, node_off, compic1, xb, mbxb);
  k_gemm2<<<NND/16, 256, 0, stream>>>(mbxb, Wt1, bias1, h1b);
  k_agg  <<<NND, 64, 0, stream>>>(sorted, node_off, compic2, h1b, mbxb);
  k_gemm2<<<NND/16, 256, 0, stream>>>(mbxb, Wt2, bias2, h2b);

  dim3 dgD((NT+63)/64, 4);
  k_dec3<<<dgD, 256, 0, stream>>>(h2b, tgt, Ms, out);
}

// Round 18
// 423.796 us; speedup vs baseline: 1.0672x; 1.0672x over previous
//
#include <hip/hip_runtime.h>
#include <hip/hip_bf16.h>
#include <math.h>

#define NND 20000      // nodes
#define NE  1000000    // edges
#define RREL 32        // relations
#define HD 128         // hidden / in dim
#define NB 8           // bases
#define NT 20000       // target edges
#define KCAT 1152      // B*IN + IN  (mb || x)
#define NBLK 128       // histogram-sort blocks
#define CHUNK ((NE + NBLK - 1) / NBLK)   // 7813 edges per block (< 65536 -> u16 counts safe)

#define ETYPE_BLKS ((NE + 255)/256)          // 3907
#define CASTX_BLKS ((NND*HD/8 + 255)/256)    // 1250
#define PREPW_BLKS ((HD*(KCAT/8) + 255)/256) // 72
#define PREP_BLKS  (RREL*8)                  // 256

typedef short bf16x8 __attribute__((ext_vector_type(8)));
typedef float f32x4 __attribute__((ext_vector_type(4)));
typedef float f32x2 __attribute__((ext_vector_type(2)));

static __device__ __forceinline__ unsigned short f2bf(float f){
  union { float f; unsigned int u; } c; c.f = f;
  unsigned int r = c.u + 0x7FFF + ((c.u >> 16) & 1);   // RNE
  return (unsigned short)(r >> 16);
}
static __device__ __forceinline__ float bf2f(unsigned short s){
  union { unsigned int u; float f; } c; c.u = ((unsigned int)s) << 16;
  return c.f;
}

// ---------- fused setup: etype | castX | prepW1 | prepW2 | prep(Ms) ----------
__global__ __launch_bounds__(256) void k_setup(
    const float* __restrict__ ea, int* __restrict__ etype,
    const float* __restrict__ x, unsigned short* __restrict__ xb,
    const float* __restrict__ bases1, const float* __restrict__ root1, unsigned short* __restrict__ Wt1,
    const float* __restrict__ bases2, const float* __restrict__ root2, unsigned short* __restrict__ Wt2,
    const float* __restrict__ Rm, const float* __restrict__ D, unsigned short* __restrict__ Ms)
{
  int bid = blockIdx.x;
  int t = threadIdx.x;
  if (bid < ETYPE_BLKS){
    int e = bid*256 + t;
    if (e >= NE) return;
    const float4* row = (const float4*)(ea + (size_t)e*RREL);
    int bi = 0;
    #pragma unroll
    for (int q=0;q<8;q++){
      float4 v = row[q];
      if (v.x > 0.5f) bi = q*4;
      if (v.y > 0.5f) bi = q*4+1;
      if (v.z > 0.5f) bi = q*4+2;
      if (v.w > 0.5f) bi = q*4+3;
    }
    etype[e] = bi;
    return;
  }
  bid -= ETYPE_BLKS;
  if (bid < CASTX_BLKS){
    int i = bid*256 + t;
    if (i >= NND*HD/8) return;
    const float4* p = (const float4*)(x + (size_t)i*8);
    float4 a = p[0], b = p[1];
    unsigned int o0 = f2bf(a.x) | ((unsigned int)f2bf(a.y)<<16);
    unsigned int o1 = f2bf(a.z) | ((unsigned int)f2bf(a.w)<<16);
    unsigned int o2 = f2bf(b.x) | ((unsigned int)f2bf(b.y)<<16);
    unsigned int o3 = f2bf(b.z) | ((unsigned int)f2bf(b.w)<<16);
    *(uint4*)(xb + (size_t)i*8) = make_uint4(o0,o1,o2,o3);
    return;
  }
  bid -= CASTX_BLKS;
  if (bid < 2*PREPW_BLKS){
    const float* bases = (bid < PREPW_BLKS) ? bases1 : bases2;
    const float* root  = (bid < PREPW_BLKS) ? root1  : root2;
    unsigned short* Wt = (bid < PREPW_BLKS) ? Wt1    : Wt2;
    int idx = (bid % PREPW_BLKS)*256 + t;
    if (idx >= HD*(KCAT/8)) return;
    int o  = idx / (KCAT/8);
    int k0 = (idx % (KCAT/8))*8;
    unsigned short tmp[8];
    #pragma unroll
    for (int q=0;q<8;q++){
      int k = k0+q;
      float v = (k < 1024) ? bases[(size_t)k*HD + o] : root[(size_t)(k-1024)*HD + o];
      tmp[q] = f2bf(v);
    }
    *(uint4*)(Wt + (size_t)o*KCAT + k0) = *(uint4*)tmp;
    return;
  }
  bid -= 2*PREPW_BLKS;
  {
    int r = bid & 31, ib = bid >> 5;
    int i = ib*16 + (t>>4);
    int j0 = (t&15)*8;
    float di = D[r*HD + i];
    float4 dj0 = *(const float4*)(D + r*HD + j0);
    float4 dj1 = *(const float4*)(D + r*HD + j0 + 4);
    float4 r0 = *(const float4*)(Rm + (size_t)i*HD + j0);
    float4 r1 = *(const float4*)(Rm + (size_t)i*HD + j0 + 4);
    unsigned int o0 = f2bf(di*dj0.x*r0.x) | ((unsigned int)f2bf(di*dj0.y*r0.y)<<16);
    unsigned int o1 = f2bf(di*dj0.z*r0.z) | ((unsigned int)f2bf(di*dj0.w*r0.w)<<16);
    unsigned int o2 = f2bf(di*dj1.x*r1.x) | ((unsigned int)f2bf(di*dj1.y*r1.y)<<16);
    unsigned int o3 = f2bf(di*dj1.z*r1.z) | ((unsigned int)f2bf(di*dj1.w*r1.w)<<16);
    *(uint4*)(Ms + (size_t)(r*HD + i)*HD + j0) = make_uint4(o0,o1,o2,o3);
  }
}

// ---------- per-block dst histogram (LDS, u16-packed) -> ghist[n][b] ----------
__global__ __launch_bounds__(1024) void k_hist(const int* __restrict__ ei,
                                               int* __restrict__ ghist)
{
  __shared__ int h[NND/2];   // 40 KB, two u16 counts per int
  int t = threadIdx.x, b = blockIdx.x;
  for (int i=t; i<NND/2; i+=1024) h[i] = 0;
  __syncthreads();
  int e0 = b*CHUNK, e1 = min(e0+CHUNK, NE);
  for (int e=e0+t; e<e1; e+=1024){
    int dst = ei[NE + e];
    atomicAdd(&h[dst>>1], 1 << ((dst&1)*16));
  }
  __syncthreads();
  for (int i=t; i<NND/2; i+=1024){
    int v = h[i];
    ghist[(size_t)(2*i  )*NBLK + b] = v & 0xFFFF;
    ghist[(size_t)(2*i+1)*NBLK + b] = (v >> 16) & 0xFFFF;
  }
}

// ---------- node_cnt[n] = sum_b ghist[n][b]  (wave per node, 2 elems/lane) ----------
__global__ __launch_bounds__(256) void k_rowsum(const int* __restrict__ ghist,
                                                int* __restrict__ node_cnt)
{
  int t = threadIdx.x;
  int n = blockIdx.x*4 + (t>>6);
  int lane = t & 63;
  int v = ghist[(size_t)n*NBLK + lane] + ghist[(size_t)n*NBLK + 64 + lane];
  #pragma unroll
  for (int d=32; d>0; d>>=1) v += __shfl_down(v, d);
  if (lane == 0) node_cnt[n] = v;
}

// ---------- single-block exclusive scan of node_cnt -> node_off ----------
__global__ __launch_bounds__(1024) void k_scan(const int* __restrict__ node_cnt,
                                               int* __restrict__ node_off)
{
  __shared__ int part[1024];
  int t = threadIdx.x;
  const int CH = (NND + 1023)/1024;   // 20
  int base = t*CH;
  int s = 0;
  for (int i=0;i<CH;i++){ int idx = base+i; if (idx<NND) s += node_cnt[idx]; }
  part[t] = s;
  __syncthreads();
  for (int d=1; d<1024; d<<=1){
    int v = part[t];
    int u = (t>=d) ? part[t-d] : 0;
    __syncthreads();
    part[t] = v + u;
    __syncthreads();
  }
  int run = (t==0) ? 0 : part[t-1];
  for (int i=0;i<CH;i++){ int idx=base+i; if (idx<NND){ node_off[idx]=run; run += node_cnt[idx]; } }
  if (t==1023) node_off[NND] = part[1023];
}

// ---------- ghist[n][b] -> absolute scatter base (128 entries: 2 elems/lane) ----------
__global__ __launch_bounds__(256) void k_scanB(int* __restrict__ ghist,
                                               const int* __restrict__ node_off)
{
  int t = threadIdx.x;
  int n = blockIdx.x*4 + (t>>6);
  int lane = t & 63;
  int v0 = ghist[(size_t)n*NBLK + lane];
  int v1 = ghist[(size_t)n*NBLK + 64 + lane];
  int x0 = v0, x1 = v1;
  #pragma unroll
  for (int d=1; d<64; d<<=1){
    int y0 = __shfl_up(x0, d);
    int y1 = __shfl_up(x1, d);
    if (lane >= d){ x0 += y0; x1 += y1; }
  }
  int T0 = __shfl(x0, 63);     // total of first 64 entries
  x1 += T0;
  int off = node_off[n];
  ghist[(size_t)n*NBLK + lane]      = off + x0 - v0;   // exclusive prefix
  ghist[(size_t)n*NBLK + 64 + lane] = off + x1 - v1;
}

// ---------- scatter replay: rank via LDS atomics, no global atomics ----------
__global__ __launch_bounds__(1024) void k_scatter2(
    const int* __restrict__ ei, const int* __restrict__ etype,
    const int* __restrict__ ghist, int2* __restrict__ sorted)
{
  __shared__ int h[NND/2];
  int t = threadIdx.x, b = blockIdx.x;
  for (int i=t; i<NND/2; i+=1024) h[i] = 0;
  __syncthreads();
  int e0 = b*CHUNK, e1 = min(e0+CHUNK, NE);
  for (int e=e0+t; e<e1; e+=1024){
    int dst = ei[NE + e];
    int sh = (dst&1)*16;
    int old = atomicAdd(&h[dst>>1], 1 << sh);
    int rank = (old >> sh) & 0xFFFF;
    int pos = ghist[(size_t)dst*NBLK + b] + rank;
    sorted[pos] = make_int2(ei[e], etype[e]);
  }
}

// ---------- per-(node,rel) inverse counts from the sorted list ----------
__global__ __launch_bounds__(256) void k_cnt(const int2* __restrict__ sorted,
                                             const int* __restrict__ node_off,
                                             float* __restrict__ inv)
{
  int t = threadIdx.x;
  int n = blockIdx.x*4 + (t>>6);
  int lane = t & 63;
  int r = lane & 31, half = lane >> 5;
  int p0 = node_off[n], p1 = node_off[n+1];
  int c = 0;
  for (int p=p0+half; p<p1; p+=2) c += (sorted[p].y == r);
  c += __shfl_down(c, 32);
  if (lane < 32) inv[(size_t)n*RREL + lane] = 1.0f / fmaxf((float)c, 1.0f);
}

// ---------- per-node aggregation: 1 wave/block (CLOSED structure), 2-edge unroll, f32x2 acc ----------
// round-16 known-good inner loop: comp (1KB, L1) + inv_cnt (2.5MB, L2) coefficients.
__global__ __launch_bounds__(64) void k_agg(
    const int2* __restrict__ sorted, const int* __restrict__ node_off,
    const float* __restrict__ inv_cnt, const float* __restrict__ comp,
    const unsigned short* __restrict__ xb, unsigned short* __restrict__ mbxb)
{
  int n = blockIdx.x;
  int lane = threadIdx.x;
  f32x2 acc[NB];
  #pragma unroll
  for (int b=0;b<NB;b++){ f32x2 z = {0.f,0.f}; acc[b] = z; }
  int p0 = node_off[n], p1 = node_off[n+1];
  const float* icr = inv_cnt + (size_t)n*RREL;

  int p = p0;
  if ((p & 1) && p < p1){
    int2 se = sorted[p];
    unsigned int vv = *(const unsigned int*)(xb + (size_t)se.x*HD + 2*lane);
    float ic = icr[se.y];
    const float4* cr = (const float4*)(comp + se.y*NB);
    float4 c0 = cr[0], c1 = cr[1];
    f32x2 xv = { bf2f((unsigned short)(vv & 0xFFFF)) * ic,
                 bf2f((unsigned short)(vv >> 16)) * ic };
    acc[0] += c0.x*xv; acc[1] += c0.y*xv; acc[2] += c0.z*xv; acc[3] += c0.w*xv;
    acc[4] += c1.x*xv; acc[5] += c1.y*xv; acc[6] += c1.z*xv; acc[7] += c1.w*xv;
    ++p;
  }
  for (; p + 2 <= p1; p += 2){
    int4 s2 = *(const int4*)(sorted + p);   // edge A=(x,y), edge B=(z,w)
    unsigned int va = *(const unsigned int*)(xb + (size_t)s2.x*HD + 2*lane);
    unsigned int vb = *(const unsigned int*)(xb + (size_t)s2.z*HD + 2*lane);
    float icA = icr[s2.y];
    float icB = icr[s2.w];
    const float4* crA = (const float4*)(comp + s2.y*NB);
    const float4* crB = (const float4*)(comp + s2.w*NB);
    float4 cA0 = crA[0], cA1 = crA[1];
    float4 cB0 = crB[0], cB1 = crB[1];
    f32x2 xa = { bf2f((unsigned short)(va & 0xFFFF)) * icA,
                 bf2f((unsigned short)(va >> 16)) * icA };
    f32x2 xv = { bf2f((unsigned short)(vb & 0xFFFF)) * icB,
                 bf2f((unsigned short)(vb >> 16)) * icB };
    acc[0] += cA0.x*xa; acc[1] += cA0.y*xa; acc[2] += cA0.z*xa; acc[3] += cA0.w*xa;
    acc[4] += cA1.x*xa; acc[5] += cA1.y*xa; acc[6] += cA1.z*xa; acc[7] += cA1.w*xa;
    acc[0] += cB0.x*xv; acc[1] += cB0.y*xv; acc[2] += cB0.z*xv; acc[3] += cB0.w*xv;
    acc[4] += cB1.x*xv; acc[5] += cB1.y*xv; acc[6] += cB1.z*xv; acc[7] += cB1.w*xv;
  }
  if (p < p1){
    int2 se = sorted[p];
    unsigned int vv = *(const unsigned int*)(xb + (size_t)se.x*HD + 2*lane);
    float ic = icr[se.y];
    const float4* cr = (const float4*)(comp + se.y*NB);
    float4 c0 = cr[0], c1 = cr[1];
    f32x2 xv = { bf2f((unsigned short)(vv & 0xFFFF)) * ic,
                 bf2f((unsigned short)(vv >> 16)) * ic };
    acc[0] += c0.x*xv; acc[1] += c0.y*xv; acc[2] += c0.z*xv; acc[3] += c0.w*xv;
    acc[4] += c1.x*xv; acc[5] += c1.y*xv; acc[6] += c1.z*xv; acc[7] += c1.w*xv;
  }

  unsigned short* o = mbxb + (size_t)n*KCAT;
  #pragma unroll
  for (int b=0;b<NB;b++){
    unsigned int u = (unsigned int)f2bf(acc[b][0]) | ((unsigned int)f2bf(acc[b][1])<<16);
    *(unsigned int*)(o + b*HD + 2*lane) = u;
  }
  *(unsigned int*)(o + 1024 + 2*lane) = *(const unsigned int*)(xb + (size_t)n*HD + 2*lane);
}

// ---------- layer GEMM via MFMA: 16 rows/block, bf16 output only ----------
__global__ __launch_bounds__(256) void k_gemm2(
    const unsigned short* __restrict__ A, const unsigned short* __restrict__ Wt,
    const float* __restrict__ bias, unsigned short* __restrict__ outB)
{
  int t = threadIdx.x, bm = blockIdx.x;       // bm in [0,1250): rows bm*16..bm*16+15
  int lane = t & 63, w = t >> 6, g = lane >> 4, c = lane & 15;
  const unsigned short* arow = A + (size_t)(bm*16 + c)*KCAT;
  const unsigned short* wt0 = Wt + (size_t)((w*2+0)*16 + c)*KCAT;
  const unsigned short* wt1 = Wt + (size_t)((w*2+1)*16 + c)*KCAT;
  f32x4 acc0 = {0.f,0.f,0.f,0.f}, acc1 = {0.f,0.f,0.f,0.f};
  #pragma unroll 4
  for (int kk=0; kk<KCAT/32; ++kk){
    int koff = kk*32 + 8*g;
    bf16x8 a  = *(const bf16x8*)(arow + koff);
    bf16x8 b0 = *(const bf16x8*)(wt0 + koff);
    bf16x8 b1 = *(const bf16x8*)(wt1 + koff);
    acc0 = __builtin_amdgcn_mfma_f32_16x16x32_bf16(a, b0, acc0, 0,0,0);
    acc1 = __builtin_amdgcn_mfma_f32_16x16x32_bf16(a, b1, acc1, 0,0,0);
  }
  int orow = bm*16 + 4*g;
  #pragma unroll
  for (int nt=0; nt<2; ++nt){
    int o = (w*2+nt)*16 + c;
    float bi = bias[o];
    f32x4 acc = nt ? acc1 : acc0;
    #pragma unroll
    for (int q=0; q<4; ++q){
      int rr = orow + q;
      outB[(size_t)rr*HD + o] = f2bf(fmaxf(acc[q] + bi, 0.f));
    }
  }
}

// ---------- DEDICOM decoder via MFMA: 64 edges x 8 relations per block, u(bf16) in registers ----------
// grid (313, 4). LDS: vb 17.4 KB + red 1.2 KB. blockIdx.y*8+rr = relation.
__global__ __launch_bounds__(256) void k_dec3(
    const unsigned short* __restrict__ h2b, const int* __restrict__ tgt,
    const unsigned short* __restrict__ Ms, float* __restrict__ out)
{
  __shared__ __align__(16) unsigned short vb[64*136];  // v rows bf16, pad 136 (2-way max)
  __shared__ __align__(16) float red[4][72];           // per-wave partials, conflict-free
  int t = threadIdx.x;
  int bm = blockIdx.x;
  int lane = t & 63, w = t >> 6, g = lane >> 4, c = lane & 15;

  // stage v rows: direct bf16 copy from h2b
  {
    int e = t >> 2, seg = t & 3;
    int eg = bm*64 + e;
    bool ok = (eg < NT);
    int n1 = ok ? tgt[NT + eg] : 0;
    const uint4* pv = (const uint4*)(h2b + (size_t)n1*HD);   // 16 uint4 per row
    unsigned int* vbr = (unsigned int*)vb + e*68;
    #pragma unroll
    for (int q=0; q<4; ++q){
      uint4 v4 = ok ? pv[seg*4+q] : make_uint4(0,0,0,0);
      *(uint4*)(vbr + (seg*4+q)*4) = v4;
    }
  }
  // u rows in registers (r-invariant), loaded bf16 and converted once
  float4 ur[4][2];
  #pragma unroll
  for (int nt=0; nt<4; ++nt){
    int eg = bm*64 + nt*16 + c;
    bool ok = (eg < NT);
    int n0 = ok ? tgt[eg] : 0;
    const unsigned short* pu = h2b + (size_t)n0*HD;
    #pragma unroll
    for (int mm=0; mm<2; ++mm){
      uint2 uu = ok ? *(const uint2*)(pu + (2*w+mm)*16 + 4*g) : make_uint2(0,0);
      ur[nt][mm] = make_float4(
        bf2f((unsigned short)(uu.x & 0xFFFF)), bf2f((unsigned short)(uu.x >> 16)),
        bf2f((unsigned short)(uu.y & 0xFFFF)), bf2f((unsigned short)(uu.y >> 16)));
    }
  }
  __syncthreads();

  for (int rr=0; rr<8; ++rr){
    int r = blockIdx.y*8 + rr;
    f32x4 acc[2][4];
    #pragma unroll
    for (int mm=0;mm<2;mm++)
      #pragma unroll
      for (int nt=0;nt<4;nt++){ f32x4 z = {0.f,0.f,0.f,0.f}; acc[mm][nt] = z; }
    #pragma unroll
    for (int kk=0; kk<4; ++kk){
      int koff = kk*32 + 8*g;
      bf16x8 a0 = *(const bf16x8*)(Ms + (size_t)(r*HD + (2*w+0)*16 + c)*HD + koff);
      bf16x8 a1 = *(const bf16x8*)(Ms + (size_t)(r*HD + (2*w+1)*16 + c)*HD + koff);
      #pragma unroll
      for (int nt=0; nt<4; ++nt){
        bf16x8 b = *(const bf16x8*)&vb[(nt*16 + c)*136 + koff];
        acc[0][nt] = __builtin_amdgcn_mfma_f32_16x16x32_bf16(a0, b, acc[0][nt], 0,0,0);
        acc[1][nt] = __builtin_amdgcn_mfma_f32_16x16x32_bf16(a1, b, acc[1][nt], 0,0,0);
      }
    }
    float s[4];
    #pragma unroll
    for (int nt=0; nt<4; ++nt){
      s[nt] = ur[nt][0].x*acc[0][nt][0] + ur[nt][0].y*acc[0][nt][1]
            + ur[nt][0].z*acc[0][nt][2] + ur[nt][0].w*acc[0][nt][3]
            + ur[nt][1].x*acc[1][nt][0] + ur[nt][1].y*acc[1][nt][1]
            + ur[nt][1].z*acc[1][nt][2] + ur[nt][1].w*acc[1][nt][3];
      s[nt] += __shfl_xor(s[nt], 16);
      s[nt] += __shfl_xor(s[nt], 32);
    }
    if (lane < 16){
      #pragma unroll
      for (int nt=0; nt<4; ++nt) red[w][nt*16 + lane] = s[nt];
    }
    __syncthreads();
    if (t < 64){
      float sum = red[0][t] + red[1][t] + red[2][t] + red[3][t];
      int eg = bm*64 + t;
      if (eg < NT) out[(size_t)eg*RREL + r] = 1.f/(1.f+expf(-sum));
    }
    __syncthreads();
  }
}

extern "C" void kernel_launch(void* const* d_in, const int* in_sizes, int n_in,
                              void* d_out, int out_size, void* d_ws, size_t ws_size,
                              hipStream_t stream)
{
  const float* x      = (const float*)d_in[0];
  const int*   ei     = (const int*)d_in[1];     // int32 (harness converts integer inputs)
  const float* ea     = (const float*)d_in[2];
  const int*   tgt    = (const int*)d_in[3];     // int32
  const float* bases1 = (const float*)d_in[4];
  const float* comp1  = (const float*)d_in[5];
  const float* root1  = (const float*)d_in[6];
  const float* bias1  = (const float*)d_in[7];
  const float* bases2 = (const float*)d_in[8];
  const float* comp2  = (const float*)d_in[9];
  const float* root2  = (const float*)d_in[10];
  const float* bias2  = (const float*)d_in[11];
  const float* Rm     = (const float*)d_in[12];
  const float* D      = (const float*)d_in[13];
  float* out = (float*)d_out;

  char* base = (char*)d_ws;
  size_t o = 0;
  auto carve = [&](size_t bytes)->char*{
    char* p = base + o;
    o += (bytes + 255) & ~(size_t)255;
    return p;
  };
  int*   etype     = (int*)  carve((size_t)NE*4);
  int*   ghist     = (int*)  carve((size_t)NND*NBLK*4);
  float* inv_cnt   = (float*)carve((size_t)NND*RREL*4);
  int*   node_cnt  = (int*)  carve((size_t)NND*4);
  int*   node_off  = (int*)  carve((size_t)(NND+1)*4);
  int2*  sorted    = (int2*) carve((size_t)NE*8);
  unsigned short* mbxb = (unsigned short*)carve((size_t)NND*KCAT*2);
  unsigned short* xb  = (unsigned short*)carve((size_t)NND*HD*2);
  unsigned short* h1b = (unsigned short*)carve((size_t)NND*HD*2);
  unsigned short* h2b = (unsigned short*)carve((size_t)NND*HD*2);
  unsigned short* Ms  = (unsigned short*)carve((size_t)RREL*HD*HD*2);
  unsigned short* Wt1 = (unsigned short*)carve((size_t)HD*KCAT*2);
  unsigned short* Wt2 = (unsigned short*)carve((size_t)HD*KCAT*2);

  if (ws_size < o) return;   // workspace too small: fail loudly (wrong output, no corruption)

  int setup_blks = ETYPE_BLKS + CASTX_BLKS + 2*PREPW_BLKS + PREP_BLKS;
  k_setup <<<setup_blks, 256, 0, stream>>>(ea, etype, x, xb,
                                           bases1, root1, Wt1,
                                           bases2, root2, Wt2,
                                           Rm, D, Ms);
  k_hist    <<<NBLK, 1024, 0, stream>>>(ei, ghist);
  k_rowsum  <<<NND/4, 256, 0, stream>>>(ghist, node_cnt);
  k_scan    <<<1, 1024, 0, stream>>>(node_cnt, node_off);
  k_scanB   <<<NND/4, 256, 0, stream>>>(ghist, node_off);
  k_scatter2<<<NBLK, 1024, 0, stream>>>(ei, etype, ghist, sorted);
  k_cnt     <<<NND/4, 256, 0, stream>>>(sorted, node_off, inv_cnt);

  k_agg  <<<NND, 64, 0, stream>>>(sorted, node_off, inv_cnt, comp1, xb, mbxb);
  k_gemm2<<<NND/16, 256, 0, stream>>>(mbxb, Wt1, bias1, h1b);
  k_agg  <<<NND, 64, 0, stream>>>(sorted, node_off, inv_cnt, comp2, h1b, mbxb);
  k_gemm2<<<NND/16, 256, 0, stream>>>(mbxb, Wt2, bias2, h2b);

  dim3 dgD((NT+63)/64, 4);
  k_dec3<<<dgD, 256, 0, stream>>>(h2b, tgt, Ms, out);
}